// Round 6
// baseline (1024.268 us; speedup 1.0000x reference)
//
#include <hip/hip_runtime.h>
#include <hip/hip_bf16.h>

typedef __hip_bfloat16 bf16;
typedef __attribute__((ext_vector_type(8))) short short8;
typedef __attribute__((ext_vector_type(4))) float f32x4;

#define TOK 100352      // B * H * W = 32*56*56
#define NWIN 2048       // B * 64 windows
#define CC 192
#define NHEAD 6
#define NT 49           // tokens per window

__device__ __forceinline__ float bf2f(bf16 v) { return __bfloat162float(v); }
__device__ __forceinline__ bf16 f2bf(float v) { return __float2bfloat16(v); }

// dtype-agnostic input load: f=1 -> fp32, f=0 -> bf16
__device__ __forceinline__ float ldin(const void* p, size_t i, int f) {
    return f ? ((const float*)p)[i] : bf2f(((const bf16*)p)[i]);
}
// typed store/load for GEMM C/resid
__device__ __forceinline__ void stc(bf16* p, float v) { *p = f2bf(v); }
__device__ __forceinline__ void stc(float* p, float v) { *p = v; }
__device__ __forceinline__ float ldc(const bf16* p) { return bf2f(*p); }
__device__ __forceinline__ float ldc(const float* p) { return *p; }

// ---------------- input dtype probe ----------------
// Interpret low halfword of each 32-bit word of x as bf16. fp32 data -> mantissa
// bits in exponent field -> ~37% huge/NaN. bf16 data -> real values -> ~0 hits.
__global__ void dtype_probe_kernel(const void* xraw, int* flag) {
    const unsigned short* u = (const unsigned short*)xraw;
    int lane = threadIdx.x & 63;
    int weird = 0;
    for (int i = lane; i < 4096; i += 64) {
        unsigned int bits = ((unsigned int)u[2 * i]) << 16;
        float v = __uint_as_float(bits);
        if (!(fabsf(v) <= 1e10f)) weird++;
    }
    #pragma unroll
    for (int off = 32; off > 0; off >>= 1) weird += __shfl_xor(weird, off, 64);
    if (lane == 0) *flag = (weird > 256) ? 1 : 0;   // 1 = fp32 inputs, 0 = bf16 inputs
}

// ---------------- weight transpose + cast: out[n*K + k] = (bf16)in[k*N + n] ----------------
__global__ void transpose_kernel(const void* __restrict__ in, bf16* __restrict__ out,
                                 int K, int N, const int* __restrict__ flag) {
    int f = *flag;
    int idx = blockIdx.x * 256 + threadIdx.x;
    if (idx >= K * N) return;
    int nn = idx / K, kk = idx % K;
    out[idx] = f2bf(ldin(in, (size_t)kk * N + nn, f));
}

// ---------------- LN1 + cyclic shift + window partition ----------------
__global__ __launch_bounds__(256) void ln1_window_kernel(
    const void* __restrict__ x, const void* __restrict__ g, const void* __restrict__ b,
    bf16* __restrict__ hwin, const int* __restrict__ flag) {
    int f = *flag;
    int wave = threadIdx.x >> 6, lane = threadIdx.x & 63;
    int t = blockIdx.x * 4 + wave;              // 0..TOK-1, window-layout index
    int bidx = t / (64 * NT);
    int r = t % (64 * NT);
    int wi = r / NT, n = r % NT;
    int wr = wi >> 3, wc = wi & 7;
    int nr = n / 7, nc = n % 7;
    int si = wr * 7 + nr, sj = wc * 7 + nc;     // shifted-image coords
    int oi = si + 3; if (oi >= 56) oi -= 56;    // source (original) coords
    int oj = sj + 3; if (oj >= 56) oj -= 56;
    size_t src = ((size_t)bidx * 3136 + oi * 56 + oj) * CC;
    float v0 = ldin(x, src + lane, f);
    float v1 = ldin(x, src + lane + 64, f);
    float v2 = ldin(x, src + lane + 128, f);
    float s = v0 + v1 + v2;
    float sq = v0 * v0 + v1 * v1 + v2 * v2;
    #pragma unroll
    for (int off = 32; off > 0; off >>= 1) {
        s  += __shfl_xor(s, off, 64);
        sq += __shfl_xor(sq, off, 64);
    }
    float mu = s * (1.f / 192.f);
    float var = fmaxf(sq * (1.f / 192.f) - mu * mu, 0.f);
    float rs = rsqrtf(var + 1e-5f);
    bf16* dst = hwin + (size_t)t * CC;
    dst[lane]       = f2bf((v0 - mu) * rs * ldin(g, lane, f)       + ldin(b, lane, f));
    dst[lane + 64]  = f2bf((v1 - mu) * rs * ldin(g, lane + 64, f)  + ldin(b, lane + 64, f));
    dst[lane + 128] = f2bf((v2 - mu) * rs * ldin(g, lane + 128, f) + ldin(b, lane + 128, f));
}

// ---------------- generic MFMA GEMM: C[M][Nc] = A[M][K] @ Wt[Nc][K]^T + bias ----------------
// EPI: 0 = none, 1 = exact GELU, 2 = add residual (resid may alias C; same-elem RMW)
template <int EPI, typename CT>
__global__ __launch_bounds__(256) void gemm_kernel(
    const bf16* __restrict__ A, const bf16* __restrict__ Wt,
    const void* __restrict__ bias, CT* C,
    const CT* resid, int M, int K, int Nc, const int* __restrict__ flag) {
    int f = *flag;
    __shared__ __align__(16) bf16 As[64 * 40];
    __shared__ __align__(16) bf16 Bs[64 * 40];
    int bn = blockIdx.x, bm = blockIdx.y;
    int tid = threadIdx.x;
    int wave = tid >> 6, lane = tid & 63;
    int quad = lane >> 4, l16 = lane & 15;
    int wm = wave >> 1, wn = wave & 1;

    f32x4 z; z[0] = z[1] = z[2] = z[3] = 0.f;
    f32x4 acc[2][2];
    acc[0][0] = z; acc[0][1] = z; acc[1][0] = z; acc[1][1] = z;

    int ldrow = tid >> 2;           // 0..63
    int ldk = (tid & 3) * 8;        // 0,8,16,24
    const bf16* Ag = A  + (size_t)(bm * 64 + ldrow) * K + ldk;
    const bf16* Wg = Wt + (size_t)(bn * 64 + ldrow) * K + ldk;

    for (int kk = 0; kk < K; kk += 32) {
        *(uint4*)(&As[ldrow * 40 + ldk]) = *(const uint4*)(Ag + kk);
        *(uint4*)(&Bs[ldrow * 40 + ldk]) = *(const uint4*)(Wg + kk);
        __syncthreads();
        short8 a0 = *(const short8*)(&As[(wm * 32 + l16) * 40 + quad * 8]);
        short8 a1 = *(const short8*)(&As[(wm * 32 + 16 + l16) * 40 + quad * 8]);
        short8 b0 = *(const short8*)(&Bs[(wn * 32 + l16) * 40 + quad * 8]);
        short8 b1 = *(const short8*)(&Bs[(wn * 32 + 16 + l16) * 40 + quad * 8]);
        acc[0][0] = __builtin_amdgcn_mfma_f32_16x16x32_bf16(a0, b0, acc[0][0], 0, 0, 0);
        acc[0][1] = __builtin_amdgcn_mfma_f32_16x16x32_bf16(a0, b1, acc[0][1], 0, 0, 0);
        acc[1][0] = __builtin_amdgcn_mfma_f32_16x16x32_bf16(a1, b0, acc[1][0], 0, 0, 0);
        acc[1][1] = __builtin_amdgcn_mfma_f32_16x16x32_bf16(a1, b1, acc[1][1], 0, 0, 0);
        __syncthreads();
    }
    #pragma unroll
    for (int tm = 0; tm < 2; tm++)
    #pragma unroll
    for (int tn = 0; tn < 2; tn++) {
        int col = bn * 64 + wn * 32 + tn * 16 + l16;
        float bv = ldin(bias, col, f);
        #pragma unroll
        for (int r = 0; r < 4; r++) {
            int row = bm * 64 + wm * 32 + tm * 16 + quad * 4 + r;
            float v = acc[tm][tn][r] + bv;
            if (EPI == 1) v = 0.5f * v * (1.0f + erff(v * 0.70710678118654752f));
            if (EPI == 2) v += ldc(&resid[(size_t)row * Nc + col]);
            stc(&C[(size_t)row * Nc + col], v);
        }
    }
}

// ---------------- naive VALU window attention (fp32 LDS) ----------------
// one block per (window, head); qkv is a chunk pointer (rows relative to wbase*NT)
__global__ __launch_bounds__(256) void attn_naive_kernel(
    const bf16* __restrict__ qkv, const void* __restrict__ rpb,
    const void* __restrict__ mask, bf16* __restrict__ attn_out, int wbase,
    const int* __restrict__ flag) {
    int f = *flag;
    __shared__ float Q[NT * 32];
    __shared__ float K[NT * 32];
    __shared__ float V[NT * 32];
    __shared__ float P[NT * 64];

    int head = blockIdx.x % NHEAD;
    int wl = blockIdx.x / NHEAD;      // window within chunk
    int wg = wbase + wl;              // global window
    int wi = wg & 63;                 // mask index (windows per image = 64)
    int t0 = wl * NT;                 // chunk-relative token base
    int tg = wg * NT;                 // global token base
    int tid = threadIdx.x;
    int wave = tid >> 6, lane = tid & 63;

    const float scale = 0.17677669529663687f;  // 1/sqrt(32)
    for (int i = tid; i < NT * 32; i += 256) {
        int n = i >> 5, d = i & 31;
        const bf16* base = qkv + (size_t)(t0 + n) * 576 + head * 32 + d;
        Q[i] = bf2f(base[0]) * scale;
        K[i] = bf2f(base[192]);
        V[i] = bf2f(base[384]);
    }
    __syncthreads();

    for (int n = wave; n < NT; n += 4) {
        float s_ = -1e9f;
        if (lane < NT) {
            float acc = 0.f;
            #pragma unroll 8
            for (int d = 0; d < 32; d++) acc += Q[n * 32 + d] * K[lane * 32 + d];
            int nr = n / 7, nc2 = n % 7, mr = lane / 7, mc = lane % 7;
            int ridx = (nr - mr + 6) * 13 + (nc2 - mc + 6);
            acc += ldin(rpb, (size_t)ridx * NHEAD + head, f);
            acc += ldin(mask, (size_t)wi * NT * NT + n * NT + lane, f);
            s_ = acc;
        }
        float mx = s_;
        #pragma unroll
        for (int off = 32; off > 0; off >>= 1) mx = fmaxf(mx, __shfl_xor(mx, off, 64));
        float e = (lane < NT) ? expf(s_ - mx) : 0.f;
        float sm = e;
        #pragma unroll
        for (int off = 32; off > 0; off >>= 1) sm += __shfl_xor(sm, off, 64);
        P[n * 64 + lane] = e / sm;
    }
    __syncthreads();

    int d = tid & 31;
    for (int n = (tid >> 5); n < NT; n += 8) {
        float acc = 0.f;
        for (int m = 0; m < NT; m++) acc += P[n * 64 + m] * V[m * 32 + d];
        attn_out[(size_t)(tg + n) * CC + head * 32 + d] = f2bf(acc);
    }
}

// ---------------- window-reverse + unshift + residual + LN2 ----------------
// x1 (FP32) goes into d_out (read back by FC2 epilogue, overwritten in place)
__global__ __launch_bounds__(256) void resid_ln2_kernel(
    const void* __restrict__ x, const bf16* __restrict__ proj,
    const void* __restrict__ g, const void* __restrict__ b,
    float* __restrict__ x1, bf16* __restrict__ h2, const int* __restrict__ flag) {
    int f = *flag;
    int wave = threadIdx.x >> 6, lane = threadIdx.x & 63;
    int tok = blockIdx.x * 4 + wave;          // original token order
    int bidx = tok / 3136;
    int r = tok % 3136;
    int i = r / 56, j = r % 56;
    int si = i + 53; if (si >= 56) si -= 56;  // (i - 3) mod 56
    int sj = j + 53; if (sj >= 56) sj -= 56;
    int wi = (si / 7) * 8 + sj / 7;
    int n = (si % 7) * 7 + (sj % 7);
    size_t tw = ((size_t)bidx * 64 + wi) * NT + n;
    const bf16* ps = proj + tw * CC;
    size_t xs = (size_t)tok * CC;
    float v0 = ldin(x, xs + lane, f)       + bf2f(ps[lane]);
    float v1 = ldin(x, xs + lane + 64, f)  + bf2f(ps[lane + 64]);
    float v2 = ldin(x, xs + lane + 128, f) + bf2f(ps[lane + 128]);
    float* xd = x1 + (size_t)tok * CC;
    xd[lane] = v0; xd[lane + 64] = v1; xd[lane + 128] = v2;
    float s = v0 + v1 + v2;
    float sq = v0 * v0 + v1 * v1 + v2 * v2;
    #pragma unroll
    for (int off = 32; off > 0; off >>= 1) {
        s  += __shfl_xor(s, off, 64);
        sq += __shfl_xor(sq, off, 64);
    }
    float mu = s * (1.f / 192.f);
    float var = fmaxf(sq * (1.f / 192.f) - mu * mu, 0.f);
    float rs = rsqrtf(var + 1e-5f);
    bf16* dst = h2 + (size_t)tok * CC;
    dst[lane]       = f2bf((v0 - mu) * rs * ldin(g, lane, f)       + ldin(b, lane, f));
    dst[lane + 64]  = f2bf((v1 - mu) * rs * ldin(g, lane + 64, f)  + ldin(b, lane + 64, f));
    dst[lane + 128] = f2bf((v2 - mu) * rs * ldin(g, lane + 128, f) + ldin(b, lane + 128, f));
}

extern "C" void kernel_launch(void* const* d_in, const int* in_sizes, int n_in,
                              void* d_out, int out_size, void* d_ws, size_t ws_size,
                              hipStream_t stream) {
    const void* x        = d_in[0];
    const void* attnmask = d_in[1];
    const void* ln1_g    = d_in[2];
    const void* ln1_b    = d_in[3];
    const void* qkv_w    = d_in[4];
    const void* qkv_b    = d_in[5];
    const void* rpb      = d_in[6];
    const void* proj_w   = d_in[7];
    const void* proj_b   = d_in[8];
    const void* ln2_g    = d_in[9];
    const void* ln2_b    = d_in[10];
    const void* fc1_w    = d_in[11];
    const void* fc1_b    = d_in[12];
    const void* fc2_w    = d_in[13];
    const void* fc2_b    = d_in[14];
    float* out = (float*)d_out;          // OUTPUT IS FP32 (reference dtype)
    char* ws = (char*)d_ws;

    // workspace layout — peak ~116.5 MB (time-disjoint region reuse):
    //   R0 [0,38.5M):       h_win [ln1 -> qkv chunks]     then m1 chunks [fc1 -> fc2]
    //   R1 [38.5M,77.1M):   attn_out [attn -> proj]       then h2        [resid -> fc1]
    //   R2 [77.1M,115.6M):  qkv chunk (28.9M) [qkv->attn] then projbuf   [proj -> resid]
    //   W  [115.6M,116.5M): transposed bf16 weights + dtype flag
    //   x1 lives in d_out (fp32), FC2 epilogue reads+overwrites in place.
    const size_t RSZ = (size_t)TOK * CC * sizeof(bf16);   // 38,535,168
    bf16* h_win    = (bf16*)(ws);
    bf16* m1buf    = (bf16*)(ws);
    bf16* attn_out = (bf16*)(ws + RSZ);
    bf16* h2       = (bf16*)(ws + RSZ);
    bf16* qkvchunk = (bf16*)(ws + 2 * RSZ);
    bf16* projbuf  = (bf16*)(ws + 2 * RSZ);
    bf16* qkvT     = (bf16*)(ws + 3 * RSZ);
    bf16* projT    = qkvT + 192 * 576;
    bf16* fc1T     = projT + 192 * 192;
    bf16* fc2T     = fc1T + 192 * 768;
    int*  flag     = (int*)(fc2T + 768 * 192);

    const int M = TOK;

    // -1) input dtype probe
    dtype_probe_kernel<<<1, 64, 0, stream>>>(x, flag);

    // 0) transpose + cast weights to bf16 [N][K]
    transpose_kernel<<<(192 * 576 + 255) / 256, 256, 0, stream>>>(qkv_w, qkvT, 192, 576, flag);
    transpose_kernel<<<(192 * 192 + 255) / 256, 256, 0, stream>>>(proj_w, projT, 192, 192, flag);
    transpose_kernel<<<(192 * 768 + 255) / 256, 256, 0, stream>>>(fc1_w, fc1T, 192, 768, flag);
    transpose_kernel<<<(768 * 192 + 255) / 256, 256, 0, stream>>>(fc2_w, fc2T, 768, 192, flag);

    // 1) LN1 + shift + window partition
    ln1_window_kernel<<<TOK / 4, 256, 0, stream>>>(x, ln1_g, ln1_b, h_win, flag);

    // 2+3) QKV GEMM + window attention, chunked over windows
    const int QCH = 4, QW = NWIN / QCH;          // 512 windows/chunk
    const int QROWS = QW * NT;                   // 25088 rows (divisible by 64)
    for (int c = 0; c < QCH; c++) {
        const bf16* a = h_win + (size_t)c * QROWS * CC;
        gemm_kernel<0, bf16><<<dim3(576 / 64, QROWS / 64), 256, 0, stream>>>(
            a, qkvT, qkv_b, qkvchunk, (const bf16*)nullptr, QROWS, 192, 576, flag);
        attn_naive_kernel<<<QW * NHEAD, 256, 0, stream>>>(
            qkvchunk, rpb, attnmask, attn_out, c * QW, flag);
    }

    // 4) proj GEMM
    gemm_kernel<0, bf16><<<dim3(192 / 64, M / 64), 256, 0, stream>>>(
        attn_out, projT, proj_b, projbuf, (const bf16*)nullptr, M, 192, 192, flag);

    // 5) window reverse + residual + LN2 (x1 fp32 -> d_out)
    resid_ln2_kernel<<<TOK / 4, 256, 0, stream>>>(x, projbuf, ln2_g, ln2_b, out, h2, flag);

    // 6+7) MLP, chunked: FC1+GELU (bf16 out) then FC2+residual (fp32, in-place on d_out)
    const int MCH = 8, MR = TOK / MCH;           // 12544 rows/chunk (divisible by 64)
    for (int c = 0; c < MCH; c++) {
        const bf16* a = h2 + (size_t)c * MR * CC;
        float* oc = out + (size_t)c * MR * CC;
        gemm_kernel<1, bf16><<<dim3(768 / 64, MR / 64), 256, 0, stream>>>(
            a, fc1T, fc1_b, m1buf, (const bf16*)nullptr, MR, 192, 768, flag);
        gemm_kernel<2, float><<<dim3(192 / 64, MR / 64), 256, 0, stream>>>(
            m1buf, fc2T, fc2_b, oc, (const float*)oc, MR, 768, 192, flag);
    }
}

// Round 7
// 856.251 us; speedup vs baseline: 1.1962x; 1.1962x over previous
//
#include <hip/hip_runtime.h>
#include <hip/hip_bf16.h>

typedef __hip_bfloat16 bf16;
typedef __attribute__((ext_vector_type(8))) short short8;
typedef __attribute__((ext_vector_type(4))) float f32x4;

#define TOK 100352      // B * H * W = 32*56*56
#define NWIN 2048       // B * 64 windows
#define CC 192
#define NHEAD 6
#define NT 49           // tokens per window

__device__ __forceinline__ float bf2f(bf16 v) { return __bfloat162float(v); }
__device__ __forceinline__ bf16 f2bf(float v) { return __float2bfloat16(v); }

// dtype-agnostic input load: f=1 -> fp32, f=0 -> bf16
__device__ __forceinline__ float ldin(const void* p, size_t i, int f) {
    return f ? ((const float*)p)[i] : bf2f(((const bf16*)p)[i]);
}
// typed store/load for GEMM C/resid
__device__ __forceinline__ void stc(bf16* p, float v) { *p = f2bf(v); }
__device__ __forceinline__ void stc(float* p, float v) { *p = v; }
__device__ __forceinline__ float ldc(const bf16* p) { return bf2f(*p); }
__device__ __forceinline__ float ldc(const float* p) { return *p; }

// ---------------- input dtype probe ----------------
__global__ void dtype_probe_kernel(const void* xraw, int* flag) {
    const unsigned short* u = (const unsigned short*)xraw;
    int lane = threadIdx.x & 63;
    int weird = 0;
    for (int i = lane; i < 4096; i += 64) {
        unsigned int bits = ((unsigned int)u[2 * i]) << 16;
        float v = __uint_as_float(bits);
        if (!(fabsf(v) <= 1e10f)) weird++;
    }
    #pragma unroll
    for (int off = 32; off > 0; off >>= 1) weird += __shfl_xor(weird, off, 64);
    if (lane == 0) *flag = (weird > 256) ? 1 : 0;   // 1 = fp32 inputs, 0 = bf16 inputs
}

// ---------------- weight transpose + cast: out[n*K + k] = (bf16)in[k*N + n] ----------------
__global__ void transpose_kernel(const void* __restrict__ in, bf16* __restrict__ out,
                                 int K, int N, const int* __restrict__ flag) {
    int f = *flag;
    int idx = blockIdx.x * 256 + threadIdx.x;
    if (idx >= K * N) return;
    int nn = idx / K, kk = idx % K;
    out[idx] = f2bf(ldin(in, (size_t)kk * N + nn, f));
}

// ---------------- LN1 + cyclic shift + window partition ----------------
__global__ __launch_bounds__(256) void ln1_window_kernel(
    const void* __restrict__ x, const void* __restrict__ g, const void* __restrict__ b,
    bf16* __restrict__ hwin, const int* __restrict__ flag) {
    int f = *flag;
    int wave = threadIdx.x >> 6, lane = threadIdx.x & 63;
    int t = blockIdx.x * 4 + wave;              // 0..TOK-1, window-layout index
    int bidx = t / (64 * NT);
    int r = t % (64 * NT);
    int wi = r / NT, n = r % NT;
    int wr = wi >> 3, wc = wi & 7;
    int nr = n / 7, nc = n % 7;
    int si = wr * 7 + nr, sj = wc * 7 + nc;     // shifted-image coords
    int oi = si + 3; if (oi >= 56) oi -= 56;    // source (original) coords
    int oj = sj + 3; if (oj >= 56) oj -= 56;
    size_t src = ((size_t)bidx * 3136 + oi * 56 + oj) * CC;
    float v0 = ldin(x, src + lane, f);
    float v1 = ldin(x, src + lane + 64, f);
    float v2 = ldin(x, src + lane + 128, f);
    float s = v0 + v1 + v2;
    float sq = v0 * v0 + v1 * v1 + v2 * v2;
    #pragma unroll
    for (int off = 32; off > 0; off >>= 1) {
        s  += __shfl_xor(s, off, 64);
        sq += __shfl_xor(sq, off, 64);
    }
    float mu = s * (1.f / 192.f);
    float var = fmaxf(sq * (1.f / 192.f) - mu * mu, 0.f);
    float rs = rsqrtf(var + 1e-5f);
    bf16* dst = hwin + (size_t)t * CC;
    dst[lane]       = f2bf((v0 - mu) * rs * ldin(g, lane, f)       + ldin(b, lane, f));
    dst[lane + 64]  = f2bf((v1 - mu) * rs * ldin(g, lane + 64, f)  + ldin(b, lane + 64, f));
    dst[lane + 128] = f2bf((v2 - mu) * rs * ldin(g, lane + 128, f) + ldin(b, lane + 128, f));
}

// ---------------- generic MFMA GEMM: C[M][Nc] = A[M][K] @ Wt[Nc][K]^T + bias ----------------
// EPI: 0 = none, 1 = exact GELU, 2 = add residual (resid may alias C; same-elem RMW)
template <int EPI, typename CT>
__global__ __launch_bounds__(256) void gemm_kernel(
    const bf16* __restrict__ A, const bf16* __restrict__ Wt,
    const void* __restrict__ bias, CT* C,
    const CT* resid, int M, int K, int Nc, const int* __restrict__ flag) {
    int f = *flag;
    __shared__ __align__(16) bf16 As[64 * 40];
    __shared__ __align__(16) bf16 Bs[64 * 40];
    int bn = blockIdx.x, bm = blockIdx.y;
    int tid = threadIdx.x;
    int wave = tid >> 6, lane = tid & 63;
    int quad = lane >> 4, l16 = lane & 15;
    int wm = wave >> 1, wn = wave & 1;

    f32x4 z; z[0] = z[1] = z[2] = z[3] = 0.f;
    f32x4 acc[2][2];
    acc[0][0] = z; acc[0][1] = z; acc[1][0] = z; acc[1][1] = z;

    int ldrow = tid >> 2;           // 0..63
    int ldk = (tid & 3) * 8;        // 0,8,16,24
    const bf16* Ag = A  + (size_t)(bm * 64 + ldrow) * K + ldk;
    const bf16* Wg = Wt + (size_t)(bn * 64 + ldrow) * K + ldk;

    for (int kk = 0; kk < K; kk += 32) {
        *(uint4*)(&As[ldrow * 40 + ldk]) = *(const uint4*)(Ag + kk);
        *(uint4*)(&Bs[ldrow * 40 + ldk]) = *(const uint4*)(Wg + kk);
        __syncthreads();
        short8 a0 = *(const short8*)(&As[(wm * 32 + l16) * 40 + quad * 8]);
        short8 a1 = *(const short8*)(&As[(wm * 32 + 16 + l16) * 40 + quad * 8]);
        short8 b0 = *(const short8*)(&Bs[(wn * 32 + l16) * 40 + quad * 8]);
        short8 b1 = *(const short8*)(&Bs[(wn * 32 + 16 + l16) * 40 + quad * 8]);
        acc[0][0] = __builtin_amdgcn_mfma_f32_16x16x32_bf16(a0, b0, acc[0][0], 0, 0, 0);
        acc[0][1] = __builtin_amdgcn_mfma_f32_16x16x32_bf16(a0, b1, acc[0][1], 0, 0, 0);
        acc[1][0] = __builtin_amdgcn_mfma_f32_16x16x32_bf16(a1, b0, acc[1][0], 0, 0, 0);
        acc[1][1] = __builtin_amdgcn_mfma_f32_16x16x32_bf16(a1, b1, acc[1][1], 0, 0, 0);
        __syncthreads();
    }
    #pragma unroll
    for (int tm = 0; tm < 2; tm++)
    #pragma unroll
    for (int tn = 0; tn < 2; tn++) {
        int col = bn * 64 + wn * 32 + tn * 16 + l16;
        float bv = ldin(bias, col, f);
        #pragma unroll
        for (int r = 0; r < 4; r++) {
            int row = bm * 64 + wm * 32 + tm * 16 + quad * 4 + r;
            float v = acc[tm][tn][r] + bv;
            if (EPI == 1) v = 0.5f * v * (1.0f + erff(v * 0.70710678118654752f));
            if (EPI == 2) v += ldc(&resid[(size_t)row * Nc + col]);
            stc(&C[(size_t)row * Nc + col], v);
        }
    }
}

// ---------------- MFMA fused window attention: one block per (window, head) ----------------
// qkv is a chunk pointer (rows relative to wbase*NT); attn_out written globally.
__global__ __launch_bounds__(256) void attn_mfma_kernel(
    const bf16* __restrict__ qkv, const void* __restrict__ rpb,
    const void* __restrict__ mask, bf16* __restrict__ attn_out, int wbase,
    const int* __restrict__ flag) {
    int f = *flag;
    __shared__ __align__(16) bf16 Qs[64 * 40];
    __shared__ __align__(16) bf16 Ks[64 * 40];
    __shared__ __align__(16) bf16 Vt[32 * 72];
    __shared__ float S[64 * 64];
    __shared__ __align__(16) bf16 P[64 * 72];

    int head = blockIdx.x % NHEAD;
    int wl = blockIdx.x / NHEAD;      // window within chunk
    int wg = wbase + wl;              // global window
    int wi = wg & 63;                 // mask index (windows per image = 64)
    int t0 = wl * NT;                 // chunk-relative token base
    int tg = wg * NT;                 // global token base
    int tid = threadIdx.x;
    int wave = tid >> 6, lane = tid & 63;
    int quad = lane >> 4, l16 = lane & 15;

    // stage Q,K (64 rows x 32, zero rows >= 49), V transposed Vt[d][m]
    {
        int row = tid >> 2;
        int dc = (tid & 3) * 8;
        uint4 qv = make_uint4(0, 0, 0, 0), kv = qv;
        if (row < NT) {
            const bf16* base = qkv + (size_t)(t0 + row) * 576 + head * 32 + dc;
            qv = *(const uint4*)(base);
            kv = *(const uint4*)(base + 192);
        }
        *(uint4*)(&Qs[row * 40 + dc]) = qv;
        *(uint4*)(&Ks[row * 40 + dc]) = kv;
        for (int idx = tid; idx < 64 * 32; idx += 256) {
            int m = idx >> 5, d = idx & 31;
            bf16 v = (m < NT) ? qkv[(size_t)(t0 + m) * 576 + 384 + head * 32 + d] : f2bf(0.f);
            Vt[d * 72 + m] = v;
        }
    }
    __syncthreads();

    // S = scale * Q K^T + rel_bias + mask  (wave tm handles rows tm*16..tm*16+15)
    const float scale = 0.17677669529663687f;  // 1/sqrt(32)
    int tm = wave;
    {
        short8 afrag = *(const short8*)(&Qs[(tm * 16 + l16) * 40 + quad * 8]);
        f32x4 z; z[0] = z[1] = z[2] = z[3] = 0.f;
        #pragma unroll
        for (int tn = 0; tn < 4; tn++) {
            short8 bfrag = *(const short8*)(&Ks[(tn * 16 + l16) * 40 + quad * 8]);
            f32x4 acc = __builtin_amdgcn_mfma_f32_16x16x32_bf16(afrag, bfrag, z, 0, 0, 0);
            int m = tn * 16 + l16;          // output col (key index)
            if (m < NT) {
                int mr = m / 7, mc = m % 7;
                #pragma unroll
                for (int r = 0; r < 4; r++) {
                    int n = tm * 16 + quad * 4 + r;   // output row (query index)
                    if (n < NT) {
                        int nr = n / 7, ncx = n % 7;
                        int ridx = (nr - mr + 6) * 13 + (ncx - mc + 6);
                        float bias = ldin(rpb, (size_t)ridx * NHEAD + head, f);
                        float mk = ldin(mask, (size_t)wi * NT * NT + n * NT + m, f);
                        S[n * 64 + m] = acc[r] * scale + bias + mk;
                    }
                }
            }
        }
    }
    __syncthreads();

    // softmax rows -> P (bf16, zero-padded rows >= 49 and cols >= 49)
    for (int n = wave; n < 64; n += 4) {
        if (n < NT) {
            float xv = (lane < NT) ? S[n * 64 + lane] : -1e30f;
            float mx = xv;
            #pragma unroll
            for (int off = 32; off > 0; off >>= 1) mx = fmaxf(mx, __shfl_xor(mx, off, 64));
            float e = (lane < NT) ? expf(xv - mx) : 0.f;
            float sm = e;
            #pragma unroll
            for (int off = 32; off > 0; off >>= 1) sm += __shfl_xor(sm, off, 64);
            P[n * 72 + lane] = f2bf(e / sm);
        } else {
            P[n * 72 + lane] = f2bf(0.f);
        }
    }
    __syncthreads();

    // O = P @ V   (M=64 rows, N=32 dims, K=64 over keys)
    f32x4 oacc[2];
    oacc[0][0] = oacc[0][1] = oacc[0][2] = oacc[0][3] = 0.f;
    oacc[1] = oacc[0];
    #pragma unroll
    for (int kc = 0; kc < 2; kc++) {
        short8 pa = *(const short8*)(&P[(tm * 16 + l16) * 72 + kc * 32 + quad * 8]);
        #pragma unroll
        for (int tn = 0; tn < 2; tn++) {
            short8 vb = *(const short8*)(&Vt[(tn * 16 + l16) * 72 + kc * 32 + quad * 8]);
            oacc[tn] = __builtin_amdgcn_mfma_f32_16x16x32_bf16(pa, vb, oacc[tn], 0, 0, 0);
        }
    }
    #pragma unroll
    for (int tn = 0; tn < 2; tn++) {
        #pragma unroll
        for (int r = 0; r < 4; r++) {
            int n = tm * 16 + quad * 4 + r;
            int d = tn * 16 + l16;
            if (n < NT)
                attn_out[(size_t)(tg + n) * CC + head * 32 + d] = f2bf(oacc[tn][r]);
        }
    }
}

// ---------------- window-reverse + unshift + residual + LN2 ----------------
// x1 (FP32) goes into d_out (read back by FC2 epilogue, overwritten in place)
__global__ __launch_bounds__(256) void resid_ln2_kernel(
    const void* __restrict__ x, const bf16* __restrict__ proj,
    const void* __restrict__ g, const void* __restrict__ b,
    float* __restrict__ x1, bf16* __restrict__ h2, const int* __restrict__ flag) {
    int f = *flag;
    int wave = threadIdx.x >> 6, lane = threadIdx.x & 63;
    int tok = blockIdx.x * 4 + wave;          // original token order
    int bidx = tok / 3136;
    int r = tok % 3136;
    int i = r / 56, j = r % 56;
    int si = i + 53; if (si >= 56) si -= 56;  // (i - 3) mod 56
    int sj = j + 53; if (sj >= 56) sj -= 56;
    int wi = (si / 7) * 8 + sj / 7;
    int n = (si % 7) * 7 + (sj % 7);
    size_t tw = ((size_t)bidx * 64 + wi) * NT + n;
    const bf16* ps = proj + tw * CC;
    size_t xs = (size_t)tok * CC;
    float v0 = ldin(x, xs + lane, f)       + bf2f(ps[lane]);
    float v1 = ldin(x, xs + lane + 64, f)  + bf2f(ps[lane + 64]);
    float v2 = ldin(x, xs + lane + 128, f) + bf2f(ps[lane + 128]);
    float* xd = x1 + (size_t)tok * CC;
    xd[lane] = v0; xd[lane + 64] = v1; xd[lane + 128] = v2;
    float s = v0 + v1 + v2;
    float sq = v0 * v0 + v1 * v1 + v2 * v2;
    #pragma unroll
    for (int off = 32; off > 0; off >>= 1) {
        s  += __shfl_xor(s, off, 64);
        sq += __shfl_xor(sq, off, 64);
    }
    float mu = s * (1.f / 192.f);
    float var = fmaxf(sq * (1.f / 192.f) - mu * mu, 0.f);
    float rs = rsqrtf(var + 1e-5f);
    bf16* dst = h2 + (size_t)tok * CC;
    dst[lane]       = f2bf((v0 - mu) * rs * ldin(g, lane, f)       + ldin(b, lane, f));
    dst[lane + 64]  = f2bf((v1 - mu) * rs * ldin(g, lane + 64, f)  + ldin(b, lane + 64, f));
    dst[lane + 128] = f2bf((v2 - mu) * rs * ldin(g, lane + 128, f) + ldin(b, lane + 128, f));
}

extern "C" void kernel_launch(void* const* d_in, const int* in_sizes, int n_in,
                              void* d_out, int out_size, void* d_ws, size_t ws_size,
                              hipStream_t stream) {
    const void* x        = d_in[0];
    const void* attnmask = d_in[1];
    const void* ln1_g    = d_in[2];
    const void* ln1_b    = d_in[3];
    const void* qkv_w    = d_in[4];
    const void* qkv_b    = d_in[5];
    const void* rpb      = d_in[6];
    const void* proj_w   = d_in[7];
    const void* proj_b   = d_in[8];
    const void* ln2_g    = d_in[9];
    const void* ln2_b    = d_in[10];
    const void* fc1_w    = d_in[11];
    const void* fc1_b    = d_in[12];
    const void* fc2_w    = d_in[13];
    const void* fc2_b    = d_in[14];
    float* out = (float*)d_out;          // output fp32 (reference dtype)
    char* ws = (char*)d_ws;

    // workspace layout — peak ~116.5 MB (time-disjoint region reuse):
    //   R0 [0,38.5M):       h_win [ln1 -> qkv chunks]     then m1 chunks [fc1 -> fc2]
    //   R1 [38.5M,77.1M):   attn_out [attn -> proj]       then h2        [resid -> fc1]
    //   R2 [77.1M,115.6M):  qkv chunk (28.9M) [qkv->attn] then projbuf   [proj -> resid]
    //   W  [115.6M,116.5M): transposed bf16 weights + dtype flag
    //   x1 lives in d_out (fp32), FC2 epilogue reads+overwrites in place.
    const size_t RSZ = (size_t)TOK * CC * sizeof(bf16);   // 38,535,168
    bf16* h_win    = (bf16*)(ws);
    bf16* m1buf    = (bf16*)(ws);
    bf16* attn_out = (bf16*)(ws + RSZ);
    bf16* h2       = (bf16*)(ws + RSZ);
    bf16* qkvchunk = (bf16*)(ws + 2 * RSZ);
    bf16* projbuf  = (bf16*)(ws + 2 * RSZ);
    bf16* qkvT     = (bf16*)(ws + 3 * RSZ);
    bf16* projT    = qkvT + 192 * 576;
    bf16* fc1T     = projT + 192 * 192;
    bf16* fc2T     = fc1T + 192 * 768;
    int*  flag     = (int*)(fc2T + 768 * 192);

    const int M = TOK;

    // -1) input dtype probe
    dtype_probe_kernel<<<1, 64, 0, stream>>>(x, flag);

    // 0) transpose + cast weights to bf16 [N][K]
    transpose_kernel<<<(192 * 576 + 255) / 256, 256, 0, stream>>>(qkv_w, qkvT, 192, 576, flag);
    transpose_kernel<<<(192 * 192 + 255) / 256, 256, 0, stream>>>(proj_w, projT, 192, 192, flag);
    transpose_kernel<<<(192 * 768 + 255) / 256, 256, 0, stream>>>(fc1_w, fc1T, 192, 768, flag);
    transpose_kernel<<<(768 * 192 + 255) / 256, 256, 0, stream>>>(fc2_w, fc2T, 768, 192, flag);

    // 1) LN1 + shift + window partition
    ln1_window_kernel<<<TOK / 4, 256, 0, stream>>>(x, ln1_g, ln1_b, h_win, flag);

    // 2+3) QKV GEMM + MFMA window attention, chunked over windows
    const int QCH = 4, QW = NWIN / QCH;          // 512 windows/chunk
    const int QROWS = QW * NT;                   // 25088 rows (divisible by 64)
    for (int c = 0; c < QCH; c++) {
        const bf16* a = h_win + (size_t)c * QROWS * CC;
        gemm_kernel<0, bf16><<<dim3(576 / 64, QROWS / 64), 256, 0, stream>>>(
            a, qkvT, qkv_b, qkvchunk, (const bf16*)nullptr, QROWS, 192, 576, flag);
        attn_mfma_kernel<<<QW * NHEAD, 256, 0, stream>>>(
            qkvchunk, rpb, attnmask, attn_out, c * QW, flag);
    }

    // 4) proj GEMM
    gemm_kernel<0, bf16><<<dim3(192 / 64, M / 64), 256, 0, stream>>>(
        attn_out, projT, proj_b, projbuf, (const bf16*)nullptr, M, 192, 192, flag);

    // 5) window reverse + residual + LN2 (x1 fp32 -> d_out)
    resid_ln2_kernel<<<TOK / 4, 256, 0, stream>>>(x, projbuf, ln2_g, ln2_b, out, h2, flag);

    // 6+7) MLP, chunked: FC1+GELU (bf16 out) then FC2+residual (fp32, in-place on d_out)
    const int MCH = 8, MR = TOK / MCH;           // 12544 rows/chunk (divisible by 64)
    for (int c = 0; c < MCH; c++) {
        const bf16* a = h2 + (size_t)c * MR * CC;
        float* oc = out + (size_t)c * MR * CC;
        gemm_kernel<1, bf16><<<dim3(768 / 64, MR / 64), 256, 0, stream>>>(
            a, fc1T, fc1_b, m1buf, (const bf16*)nullptr, MR, 192, 768, flag);
        gemm_kernel<2, float><<<dim3(192 / 64, MR / 64), 256, 0, stream>>>(
            m1buf, fc2T, fc2_b, oc, (const float*)oc, MR, 768, 192, flag);
    }
}